// Round 11
// baseline (61.392 us; speedup 1.0000x reference)
//
#include <hip/hip_runtime.h>
#include <math.h>

#define HH 640
#define WW 640
#define HWSZ (HH*WW)
#define NPTS 200000
#define NB 8
#define TPB 256
#define NACC 17     // weighted moments: cnt, sw, swA[3], swB[3], swAB[9]
#define NBPB 131    // blocks per batch
#define NPB (NBPB*TPB)
#define PPT 6       // strided points per thread; NPB*PPT = 201216 >= NPTS

typedef float vf2 __attribute__((ext_vector_type(2)));
typedef int   vi2 __attribute__((ext_vector_type(2)));

// ---------------------------------------------------------------------------
// Kernel 1: per-batch WEIGHTED moment reduction, direct f32 gathers.
// (Pack kernel removed: 3 gathers/point from the raw images; images are
// L2/L3-resident and quantization error disappears.)
// Out-of-range points: clamped index + forced weight 0 => zero contribution.
// acc: [0]=count(w>0) [1]=sw [2..4]=sw*A [5..7]=sw*B [8..16]=sw*A_i*B_j
// ---------------------------------------------------------------------------
__global__ __launch_bounds__(TPB, 4) void reduce_stats(
    const float* __restrict__ static_flow,
    const float* __restrict__ staticness,
    const float* __restrict__ pc,
    const vi2*   __restrict__ coords,
    const int*   __restrict__ valid,
    double* __restrict__ partials)           // (B,NBPB,NACC)
{
    const int bid   = blockIdx.x;
    const int b     = bid & 7;               // batch -> XCD pin (perf heuristic)
    const int chunk = bid >> 3;
    const int tid   = threadIdx.x;
    const int t     = chunk * TPB + tid;

    const vf2* pcb = (const vf2*)(pc + (size_t)b * NPTS * 6);
    const vi2* cb  = coords + (size_t)b * NPTS;
    const int* vb  = valid + (size_t)b * NPTS;
    const float* fx_img = static_flow + (size_t)b * 2 * HWSZ;
    const float* fy_img = fx_img + HWSZ;
    const float* st_img = staticness + (size_t)b * HWSZ;

    // ---- stage phase 1: stream loads (27 independent instrs) ----
    float ax[PPT], ay[PPT], az[PPT];
    int   vld[PPT], off[PPT];
    #pragma unroll
    for (int k = 0; k < PPT; ++k) {
        int n = t + k * NPB;
        bool inr = (n < NPTS);
        int nc = inr ? n : 0;
        vf2 p01 = pcb[(size_t)nc * 3];
        vf2 p23 = pcb[(size_t)nc * 3 + 1];
        vf2 p45 = pcb[(size_t)nc * 3 + 2];
        vi2 xy  = cb[nc];
        vld[k]  = inr ? vb[nc] : 0;          // weight 0 => zero contribution
        ax[k] = p01.x + p23.y;
        ay[k] = p01.y + p45.x;
        az[k] = p23.x + p45.y;
        off[k] = xy.x * WW + xy.y;
    }
    // ---- stage phase 2: gathers (3*PPT independent) ----
    float fxg[PPT], fyg[PPT], svg[PPT];
    #pragma unroll
    for (int k = 0; k < PPT; ++k) {
        fxg[k] = fx_img[off[k]];
        fyg[k] = fy_img[off[k]];
        svg[k] = st_img[off[k]];
    }

    // ---- accumulate (f32, weighted moments only) ----
    float acc[NACC];
    #pragma unroll
    for (int i = 0; i < NACC; ++i) acc[i] = 0.0f;
    #pragma unroll
    for (int k = 0; k < PPT; ++k) {
        float Ax = ax[k], Ay = ay[k], Az = az[k];
        float wf = (vld[k] != 0) ? svg[k] : 0.0f;
        float Bx = Ax + fxg[k], By = Ay + fyg[k], Bz = Az;
        float wAx = wf * Ax, wAy = wf * Ay, wAz = wf * Az;
        acc[0] += (wf > 0.0f) ? 1.0f : 0.0f;
        acc[1] += wf;
        acc[2] += wAx;      acc[3] += wAy;      acc[4] += wAz;
        acc[5] += wf * Bx;  acc[6] += wf * By;  acc[7] += wf * Bz;
        acc[8]  += wAx * Bx; acc[9]  += wAx * By; acc[10] += wAx * Bz;
        acc[11] += wAy * Bx; acc[12] += wAy * By; acc[13] += wAy * Bz;
        acc[14] += wAz * Bx; acc[15] += wAz * By; acc[16] += wAz * Bz;
    }

    // ---- LDS-transpose block reduction ----
    __shared__ float xch[TPB][NACC + 1];
    #pragma unroll
    for (int i = 0; i < NACC; ++i) xch[tid][i] = acc[i];
    __syncthreads();
    const int a = tid & 31, g = tid >> 5;
    float s = 0.0f;
    if (a < NACC) {
        #pragma unroll
        for (int k = 0; k < 32; ++k) s += xch[g * 32 + k][a];
    }
    __syncthreads();
    if (a < NACC) xch[g][a] = s;
    __syncthreads();
    if (tid < NACC) {
        double tot = 0.0;
        #pragma unroll
        for (int k = 0; k < 8; ++k) tot += (double)xch[k][tid];
        partials[((size_t)b * NBPB + chunk) * NACC + tid] = tot;
    }
}

// ---------------------------------------------------------------------------
// Kernel 2: fused solve + eval.
// Prologue (every block, redundant & deterministic): final-reduce the f64
// partials (half-wave per batch, lane i sums acc i over 131 chunks) and run
// the polar-Newton solve (8 batches on 8 SIMD-parallel lanes). Block 0 writes
// T to the d_out tail. Then all threads evaluate 4 pixels of
// flow = (T - I) @ [x, y, 0, 1].
// ---------------------------------------------------------------------------
__global__ __launch_bounds__(TPB) void solve_eval(
    const double* __restrict__ partials,
    const float*  __restrict__ vox,
    float* __restrict__ out,                 // (B,2,H,W)
    float* __restrict__ Tout)                // (B,4,4) at d_out tail
{
    __shared__ double fin[NB][NACC];
    __shared__ float  cf[NB][6];
    const int tid  = threadIdx.x;
    const int wave = tid >> 6, lane = tid & 63;
    const int half = lane >> 5, i = lane & 31;
    const int b    = wave + half * 4;        // 4 waves x 2 halves = 8 batches

    if (i < NACC) {
        double s = 0.0;
        const double* src = partials + (size_t)b * NBPB * NACC + i;
        for (int p = 0; p < NBPB; ++p) s += src[(size_t)p * NACC];
        fin[b][i] = s;
    }
    __syncthreads();

    if (tid < NB) {   // 8 parallel lanes, one batch each
        const int bb = tid;
        double sw = fin[bb][1];
        double T[12];  // rows 0..2 of T (r0 r1 r2 t)
        if (!(sw > 1e-30)) {
            for (int k = 0; k < 12; ++k) T[k] = 0.0;
            T[0] = T[5] = T[10] = 1.0;
        } else {
            double rsw = 1.0 / sw;
            double am[3], bm[3];
            for (int k = 0; k < 3; ++k) { am[k] = fin[bb][2 + k] * rsw; bm[k] = fin[bb][5 + k] * rsw; }
            double X[9];
            for (int ii = 0; ii < 3; ++ii)
                for (int j = 0; j < 3; ++j)
                    X[ii * 3 + j] = fin[bb][8 + ii * 3 + j] * rsw - am[ii] * bm[j];
            for (int it = 0; it < 12; ++it) {
                double c00 = X[4] * X[8] - X[5] * X[7];
                double c01 = X[5] * X[6] - X[3] * X[8];
                double c02 = X[3] * X[7] - X[4] * X[6];
                double det = X[0] * c00 + X[1] * c01 + X[2] * c02;
                if (!(fabs(det) > 1e-290)) break;
                double rd = 1.0 / det;
                double inv[9];
                inv[0] = c00 * rd; inv[1] = (X[2] * X[7] - X[1] * X[8]) * rd; inv[2] = (X[1] * X[5] - X[2] * X[4]) * rd;
                inv[3] = c01 * rd; inv[4] = (X[0] * X[8] - X[2] * X[6]) * rd; inv[5] = (X[2] * X[3] - X[0] * X[5]) * rd;
                inv[6] = c02 * rd; inv[7] = (X[1] * X[6] - X[0] * X[7]) * rd; inv[8] = (X[0] * X[4] - X[1] * X[3]) * rd;
                double nx = 0.0, ni = 0.0;
                for (int k = 0; k < 9; ++k) { nx += X[k] * X[k]; ni += inv[k] * inv[k]; }
                double mu = sqrt(sqrt(ni / nx)), rmu = 1.0 / mu;
                double Xn[9], d2 = 0.0;
                for (int ii = 0; ii < 3; ++ii)
                    for (int j = 0; j < 3; ++j) {
                        double v = 0.5 * (mu * X[ii * 3 + j] + inv[j * 3 + ii] * rmu);
                        double d = v - X[ii * 3 + j];
                        d2 += d * d;
                        Xn[ii * 3 + j] = v;
                    }
                for (int k = 0; k < 9; ++k) X[k] = Xn[k];
                if (d2 < 1e-26) break;
            }
            // R = V U^T = X^T; t = bm - R am
            for (int ii = 0; ii < 3; ++ii) {
                T[ii * 4 + 0] = X[0 * 3 + ii];
                T[ii * 4 + 1] = X[1 * 3 + ii];
                T[ii * 4 + 2] = X[2 * 3 + ii];
                T[ii * 4 + 3] = bm[ii] - (X[ii] * am[0] + X[3 + ii] * am[1] + X[6 + ii] * am[2]);
            }
        }
        cf[bb][0] = (float)(T[0] - 1.0);
        cf[bb][1] = (float)T[1];
        cf[bb][2] = (float)T[3];
        cf[bb][3] = (float)T[4];
        cf[bb][4] = (float)(T[5] - 1.0);
        cf[bb][5] = (float)T[7];
        if (blockIdx.x == 0) {
            float* Tb = Tout + bb * 16;
            for (int k = 0; k < 12; ++k) Tb[k] = (float)T[k];
            Tb[12] = 0.0f; Tb[13] = 0.0f; Tb[14] = 0.0f; Tb[15] = 1.0f;
        }
    }
    __syncthreads();

    // ---- eval: 4 pixels/thread, float4 stores ----
    const int p4 = blockIdx.x * blockDim.x + tid;   // pixels 4*p4 .. 4*p4+3
    if (p4 >= HWSZ / 4) return;
    float4 v01 = ((const float4*)vox)[p4 * 2];      // x0 y0 x1 y1
    float4 v23 = ((const float4*)vox)[p4 * 2 + 1];  // x2 y2 x3 y3
    #pragma unroll
    for (int bb = 0; bb < NB; ++bb) {
        float c0 = cf[bb][0], c1 = cf[bb][1], c2 = cf[bb][2];
        float c3 = cf[bb][3], c4 = cf[bb][4], c5 = cf[bb][5];
        float4 ox = make_float4(c0 * v01.x + c1 * v01.y + c2,
                                c0 * v01.z + c1 * v01.w + c2,
                                c0 * v23.x + c1 * v23.y + c2,
                                c0 * v23.z + c1 * v23.w + c2);
        float4 oy = make_float4(c3 * v01.x + c4 * v01.y + c5,
                                c3 * v01.z + c4 * v01.w + c5,
                                c3 * v23.x + c4 * v23.y + c5,
                                c3 * v23.z + c4 * v23.w + c5);
        ((float4*)(out + (size_t)(bb * 2 + 0) * HWSZ))[p4] = ox;
        ((float4*)(out + (size_t)(bb * 2 + 1) * HWSZ))[p4] = oy;
    }
}

extern "C" void kernel_launch(void* const* d_in, const int* in_sizes, int n_in,
                              void* d_out, int out_size, void* d_ws, size_t ws_size,
                              hipStream_t stream) {
    const float* static_flow = (const float*)d_in[0];
    const float* staticness  = (const float*)d_in[1];
    const float* pc          = (const float*)d_in[2];
    const vi2*   coords      = (const vi2*)d_in[3];
    const int*   valid       = (const int*)d_in[4];
    const float* vox         = (const float*)d_in[5];

    float* out  = (float*)d_out;
    float* Tout = out + (size_t)NB * 2 * HWSZ;

    double* partials = (double*)d_ws;   // 143 KB; ws proven >= 13.6 MB (round 5)

    reduce_stats<<<NBPB * NB, TPB, 0, stream>>>(
        static_flow, staticness, pc, coords, valid, partials);
    solve_eval<<<HWSZ / 4 / TPB, TPB, 0, stream>>>(partials, vox, out, Tout);
}

// Round 12
// 43.663 us; speedup vs baseline: 1.4060x; 1.4060x over previous
//
#include <hip/hip_runtime.h>
#include <math.h>

#define HH 640
#define WW 640
#define HWSZ (HH*WW)
#define NPTS 200000
#define NB 8
#define TPB 256
#define NACC 17     // weighted moments: cnt, sw, swA[3], swB[3], swAB[9]
#define NBPB 131    // blocks per batch
#define NPB (NBPB*TPB)
#define PPT 6       // strided points per thread; NPB*PPT = 201216 >= NPTS

typedef float vf2 __attribute__((ext_vector_type(2)));
typedef int   vi2 __attribute__((ext_vector_type(2)));
typedef unsigned int vu4 __attribute__((ext_vector_type(4)));

// ---------------------------------------------------------------------------
// Kernel 0: pack fx,fy -> 12-bit fixed (step 1/256, range [-8,8)), s -> 8-bit.
// 4 B/pixel => 1.64 MB/batch, fits own-XCD L2. (Round 11 proved removing this
// costs +30 us: 3 gathers/pt into a 4.8 MB/batch footprint misses L2.)
// ---------------------------------------------------------------------------
__global__ __launch_bounds__(TPB) void pack_q32(
    const float* __restrict__ static_flow, const float* __restrict__ staticness,
    unsigned int* __restrict__ packed)
{
    const int bid = blockIdx.x;
    const int b   = bid & 7;
    const int p4  = (bid >> 3) * TPB + threadIdx.x;
    if (p4 >= HWSZ / 4) return;
    const float4* fx4 = (const float4*)(static_flow + (size_t)b * 2 * HWSZ);
    const float4* fy4 = (const float4*)(static_flow + (size_t)b * 2 * HWSZ + HWSZ);
    const float4* st4 = (const float4*)(staticness + (size_t)b * HWSZ);
    float4 fx = fx4[p4], fy = fy4[p4], st = st4[p4];
    float fxa[4] = {fx.x, fx.y, fx.z, fx.w};
    float fya[4] = {fy.x, fy.y, fy.z, fy.w};
    float sta[4] = {st.x, st.y, st.z, st.w};
    vu4 v;
    #pragma unroll
    for (int j = 0; j < 4; ++j) {
        int qx = __float2int_rn((fminf(fmaxf(fxa[j], -8.0f), 7.99f) + 8.0f) * 256.0f);
        int qy = __float2int_rn((fminf(fmaxf(fya[j], -8.0f), 7.99f) + 8.0f) * 256.0f);
        int qs = __float2int_rn(fminf(fmaxf(sta[j], 0.0f), 1.0f) * 255.0f);
        qx = qx < 0 ? 0 : (qx > 4095 ? 4095 : qx);
        qy = qy < 0 ? 0 : (qy > 4095 ? 4095 : qy);
        qs = qs < 0 ? 0 : (qs > 255 ? 255 : qs);
        v[j] = (unsigned)qx | ((unsigned)qy << 12) | ((unsigned)qs << 24);
    }
    ((vu4*)(packed + (size_t)b * HWSZ))[p4] = v;
}

// ---------------------------------------------------------------------------
// Kernel 1: per-batch WEIGHTED moment reduction (round-10 proven structure).
// Strided PPT=6, staged loads, f32 accum, LDS-transpose block reduce.
// Partials TRANSPOSED to (B, NACC, NBPB): final reduce reads contiguous rows.
// MODE 0: direct f32 gathers (fallback)   MODE 1: packed u32 gather
// ---------------------------------------------------------------------------
template<int MODE>
__global__ __launch_bounds__(TPB, 4) void reduce_stats_k(
    const float* __restrict__ static_flow,
    const float* __restrict__ staticness,
    const unsigned int* __restrict__ packed,
    const float* __restrict__ pc,
    const vi2*   __restrict__ coords,
    const int*   __restrict__ valid,
    double* __restrict__ partials)           // (B,NACC,NBPB)
{
    const int bid   = blockIdx.x;
    const int b     = bid & 7;               // batch -> XCD pin (perf heuristic)
    const int chunk = bid >> 3;
    const int tid   = threadIdx.x;
    const int t     = chunk * TPB + tid;

    const vf2* pcb = (const vf2*)(pc + (size_t)b * NPTS * 6);
    const vi2* cb  = coords + (size_t)b * NPTS;
    const int* vb  = valid + (size_t)b * NPTS;
    const float* fx_img = static_flow + (size_t)b * 2 * HWSZ;
    const float* fy_img = fx_img + HWSZ;
    const float* st_img = staticness + (size_t)b * HWSZ;
    const unsigned int* img32 = packed + (size_t)b * HWSZ;

    // ---- stage phase 1: stream loads (27 independent instrs) ----
    float ax[PPT], ay[PPT], az[PPT];
    int   vld[PPT], off[PPT];
    #pragma unroll
    for (int k = 0; k < PPT; ++k) {
        int n = t + k * NPB;
        bool inr = (n < NPTS);
        int nc = inr ? n : 0;
        vf2 p01 = pcb[(size_t)nc * 3];
        vf2 p23 = pcb[(size_t)nc * 3 + 1];
        vf2 p45 = pcb[(size_t)nc * 3 + 2];
        vi2 xy  = cb[nc];
        vld[k]  = inr ? vb[nc] : 0;          // weight 0 => zero contribution
        ax[k] = p01.x + p23.y;
        ay[k] = p01.y + p45.x;
        az[k] = p23.x + p45.y;
        off[k] = xy.x * WW + xy.y;
    }
    // ---- stage phase 2: gathers (PPT independent) ----
    unsigned gw[PPT];
    float fxg[PPT], fyg[PPT], svg[PPT];
    #pragma unroll
    for (int k = 0; k < PPT; ++k) {
        if (MODE == 1) gw[k] = img32[off[k]];
        else { fxg[k] = fx_img[off[k]]; fyg[k] = fy_img[off[k]]; svg[k] = st_img[off[k]]; }
    }

    // ---- accumulate (f32, weighted moments only) ----
    float acc[NACC];
    #pragma unroll
    for (int i = 0; i < NACC; ++i) acc[i] = 0.0f;
    #pragma unroll
    for (int k = 0; k < PPT; ++k) {
        float fx, fy, s;
        if (MODE == 1) {
            unsigned w = gw[k];
            fx = (float)(int)(w & 0xFFFu) * (1.0f / 256.0f) - 8.0f;
            fy = (float)(int)((w >> 12) & 0xFFFu) * (1.0f / 256.0f) - 8.0f;
            s  = (float)(int)(w >> 24) * (1.0f / 255.0f);
        } else { fx = fxg[k]; fy = fyg[k]; s = svg[k]; }
        float Ax = ax[k], Ay = ay[k], Az = az[k];
        float wf = (vld[k] != 0) ? s : 0.0f;
        float Bx = Ax + fx, By = Ay + fy, Bz = Az;
        float wAx = wf * Ax, wAy = wf * Ay, wAz = wf * Az;
        acc[0] += (wf > 0.0f) ? 1.0f : 0.0f;
        acc[1] += wf;
        acc[2] += wAx;      acc[3] += wAy;      acc[4] += wAz;
        acc[5] += wf * Bx;  acc[6] += wf * By;  acc[7] += wf * Bz;
        acc[8]  += wAx * Bx; acc[9]  += wAx * By; acc[10] += wAx * Bz;
        acc[11] += wAy * Bx; acc[12] += wAy * By; acc[13] += wAy * Bz;
        acc[14] += wAz * Bx; acc[15] += wAz * By; acc[16] += wAz * Bz;
    }

    // ---- LDS-transpose block reduction ----
    __shared__ float xch[TPB][NACC + 1];
    #pragma unroll
    for (int i = 0; i < NACC; ++i) xch[tid][i] = acc[i];
    __syncthreads();
    const int a = tid & 31, g = tid >> 5;
    float s = 0.0f;
    if (a < NACC) {
        #pragma unroll
        for (int k = 0; k < 32; ++k) s += xch[g * 32 + k][a];
    }
    __syncthreads();
    if (a < NACC) xch[g][a] = s;
    __syncthreads();
    if (tid < NACC) {
        double tot = 0.0;
        #pragma unroll
        for (int k = 0; k < 8; ++k) tot += (double)xch[k][tid];
        partials[((size_t)b * NACC + tid) * NBPB + chunk] = tot;
    }
}

// ---------------------------------------------------------------------------
// Kernel 2: fused solve + eval (round-11 proven).
// Prologue per block (redundant, deterministic): sum each (b,acc) row of the
// transposed partials (contiguous, 4-way unrolled), 8-lane-parallel polar
// Newton, block 0 writes T. Then 4 pixels/thread flow eval.
// ---------------------------------------------------------------------------
__global__ __launch_bounds__(TPB) void solve_eval(
    const double* __restrict__ partials,     // (B,NACC,NBPB)
    const float*  __restrict__ vox,
    float* __restrict__ out,                 // (B,2,H,W)
    float* __restrict__ Tout)                // (B,4,4) at d_out tail
{
    __shared__ double fin[NB][NACC];
    __shared__ float  cf[NB][6];
    const int tid = threadIdx.x;

    if (tid < NB * NACC) {
        const int b = tid / NACC, i = tid % NACC;
        const double* src = partials + ((size_t)b * NACC + i) * NBPB;
        double s0 = 0.0, s1 = 0.0, s2 = 0.0, s3 = 0.0;
        int p = 0;
        for (; p + 4 <= NBPB; p += 4) {
            s0 += src[p]; s1 += src[p + 1]; s2 += src[p + 2]; s3 += src[p + 3];
        }
        for (; p < NBPB; ++p) s0 += src[p];
        fin[b][i] = (s0 + s1) + (s2 + s3);
    }
    __syncthreads();

    if (tid < NB) {   // 8 parallel lanes, one batch each
        const int bb = tid;
        double sw = fin[bb][1];
        double T[12];
        if (!(sw > 1e-30)) {
            for (int k = 0; k < 12; ++k) T[k] = 0.0;
            T[0] = T[5] = T[10] = 1.0;
        } else {
            double rsw = 1.0 / sw;
            double am[3], bm[3];
            for (int k = 0; k < 3; ++k) { am[k] = fin[bb][2 + k] * rsw; bm[k] = fin[bb][5 + k] * rsw; }
            double X[9];
            for (int ii = 0; ii < 3; ++ii)
                for (int j = 0; j < 3; ++j)
                    X[ii * 3 + j] = fin[bb][8 + ii * 3 + j] * rsw - am[ii] * bm[j];
            for (int it = 0; it < 8; ++it) {
                double c00 = X[4] * X[8] - X[5] * X[7];
                double c01 = X[5] * X[6] - X[3] * X[8];
                double c02 = X[3] * X[7] - X[4] * X[6];
                double det = X[0] * c00 + X[1] * c01 + X[2] * c02;
                if (!(fabs(det) > 1e-290)) break;
                double rd = 1.0 / det;
                double inv[9];
                inv[0] = c00 * rd; inv[1] = (X[2] * X[7] - X[1] * X[8]) * rd; inv[2] = (X[1] * X[5] - X[2] * X[4]) * rd;
                inv[3] = c01 * rd; inv[4] = (X[0] * X[8] - X[2] * X[6]) * rd; inv[5] = (X[2] * X[3] - X[0] * X[5]) * rd;
                inv[6] = c02 * rd; inv[7] = (X[1] * X[6] - X[0] * X[7]) * rd; inv[8] = (X[0] * X[4] - X[1] * X[3]) * rd;
                double nx = 0.0, ni = 0.0;
                for (int k = 0; k < 9; ++k) { nx += X[k] * X[k]; ni += inv[k] * inv[k]; }
                double mu = sqrt(sqrt(ni / nx)), rmu = 1.0 / mu;
                double Xn[9], d2 = 0.0;
                for (int ii = 0; ii < 3; ++ii)
                    for (int j = 0; j < 3; ++j) {
                        double v = 0.5 * (mu * X[ii * 3 + j] + inv[j * 3 + ii] * rmu);
                        double d = v - X[ii * 3 + j];
                        d2 += d * d;
                        Xn[ii * 3 + j] = v;
                    }
                for (int k = 0; k < 9; ++k) X[k] = Xn[k];
                if (d2 < 1e-26) break;
            }
            for (int ii = 0; ii < 3; ++ii) {
                T[ii * 4 + 0] = X[0 * 3 + ii];
                T[ii * 4 + 1] = X[1 * 3 + ii];
                T[ii * 4 + 2] = X[2 * 3 + ii];
                T[ii * 4 + 3] = bm[ii] - (X[ii] * am[0] + X[3 + ii] * am[1] + X[6 + ii] * am[2]);
            }
        }
        cf[bb][0] = (float)(T[0] - 1.0);
        cf[bb][1] = (float)T[1];
        cf[bb][2] = (float)T[3];
        cf[bb][3] = (float)T[4];
        cf[bb][4] = (float)(T[5] - 1.0);
        cf[bb][5] = (float)T[7];
        if (blockIdx.x == 0) {
            float* Tb = Tout + bb * 16;
            for (int k = 0; k < 12; ++k) Tb[k] = (float)T[k];
            Tb[12] = 0.0f; Tb[13] = 0.0f; Tb[14] = 0.0f; Tb[15] = 1.0f;
        }
    }
    __syncthreads();

    // ---- eval: 4 pixels/thread, float4 stores ----
    const int p4 = blockIdx.x * blockDim.x + tid;
    if (p4 >= HWSZ / 4) return;
    float4 v01 = ((const float4*)vox)[p4 * 2];
    float4 v23 = ((const float4*)vox)[p4 * 2 + 1];
    #pragma unroll
    for (int bb = 0; bb < NB; ++bb) {
        float c0 = cf[bb][0], c1 = cf[bb][1], c2 = cf[bb][2];
        float c3 = cf[bb][3], c4 = cf[bb][4], c5 = cf[bb][5];
        float4 ox = make_float4(c0 * v01.x + c1 * v01.y + c2,
                                c0 * v01.z + c1 * v01.w + c2,
                                c0 * v23.x + c1 * v23.y + c2,
                                c0 * v23.z + c1 * v23.w + c2);
        float4 oy = make_float4(c3 * v01.x + c4 * v01.y + c5,
                                c3 * v01.z + c4 * v01.w + c5,
                                c3 * v23.x + c4 * v23.y + c5,
                                c3 * v23.z + c4 * v23.w + c5);
        ((float4*)(out + (size_t)(bb * 2 + 0) * HWSZ))[p4] = ox;
        ((float4*)(out + (size_t)(bb * 2 + 1) * HWSZ))[p4] = oy;
    }
}

extern "C" void kernel_launch(void* const* d_in, const int* in_sizes, int n_in,
                              void* d_out, int out_size, void* d_ws, size_t ws_size,
                              hipStream_t stream) {
    const float* static_flow = (const float*)d_in[0];
    const float* staticness  = (const float*)d_in[1];
    const float* pc          = (const float*)d_in[2];
    const vi2*   coords      = (const vi2*)d_in[3];
    const int*   valid       = (const int*)d_in[4];
    const float* vox         = (const float*)d_in[5];

    float* out  = (float*)d_out;
    float* Tout = out + (size_t)NB * 2 * HWSZ;

    const size_t packed32 = (size_t)NB * HWSZ * 4;           // 13.1 MB
    const size_t partsz   = (size_t)NB * NACC * NBPB * 8;    // 143 KB
    char* wsc = (char*)d_ws;
    const int pack_grid = (HWSZ / 4 / TPB) * NB;             // 3200

    if (ws_size >= packed32 + partsz) {
        unsigned int* packed = (unsigned int*)wsc;
        double* partials = (double*)(wsc + packed32);
        pack_q32<<<pack_grid, TPB, 0, stream>>>(static_flow, staticness, packed);
        reduce_stats_k<1><<<NBPB * NB, TPB, 0, stream>>>(
            static_flow, staticness, packed, pc, coords, valid, partials);
        solve_eval<<<HWSZ / 4 / TPB, TPB, 0, stream>>>(partials, vox, out, Tout);
    } else {
        double* partials = (double*)wsc;
        reduce_stats_k<0><<<NBPB * NB, TPB, 0, stream>>>(
            static_flow, staticness, nullptr, pc, coords, valid, partials);
        solve_eval<<<HWSZ / 4 / TPB, TPB, 0, stream>>>(partials, vox, out, Tout);
    }
}